// Round 4
// baseline (194.737 us; speedup 1.0000x reference)
//
#include <hip/hip_runtime.h>
#include <hip/hip_bf16.h>

// GraphSAGE: out = normalize( [x, segsum(vals*x[cols], rows)] @ W^T + b )
// N=100000, E=1600000, IN_F=128, OUT_F=128.
//
// Round 8: contiguous-gather restructure. All previous gathers were 64-lane
// instructions spanning 4 random 256B rows (16 scattered 64B segments) ->
// suspected TA address-divergence serialization as the invariant ~2.4 TB/s
// cap. Now: one gather instruction = ONE row, 64 lanes x 4B contiguous
// (saddr + voffset form). Wave walks its 4 nodes' flat contiguous edge range
// (no wave-max dummy padding); ring of 8 dword loads in VGPRs (static
// unroll); per-edge dest packed in high bits of staged col; flush-on-change
// into pre-zeroed nbLDS (2 features/lane, stride-1).
// LDS 25->8.9 KB, VGPR ~60 -> up to 8 blocks/CU.
//
// ws layout:
//   [0    , ~400K)  row_ptr (int[N+1])
//   [448K , 512K)   Wf: fragment-major bf16 W, 4096 x 16B
//   [640K , +25.6M) xb: bf16(x), N x 128 (rows of 16 uint4)

typedef __bf16 bf16x8_t __attribute__((ext_vector_type(8)));
typedef float f32x4_t __attribute__((ext_vector_type(4)));
typedef float f32x2_t __attribute__((ext_vector_type(2)));
typedef unsigned int u32x4_t __attribute__((ext_vector_type(4)));

#define DESC_CAP 512   // max staged edges per block (mean 256, 16 sigma)
#define RING_D   8     // gather rows in flight per wave

__device__ __forceinline__ unsigned int f32_to_bf16(float f) {
    unsigned int u = __float_as_uint(f);
    unsigned int r = u + 0x7fffu + ((u >> 16) & 1u);   // RNE (no NaN inputs)
    return r >> 16;
}
__device__ __forceinline__ unsigned int pack2(float a, float b) {
    return f32_to_bf16(a) | (f32_to_bf16(b) << 16);
}
__device__ __forceinline__ float bflo(unsigned int p) { return __uint_as_float(p << 16); }
__device__ __forceinline__ float bfhi(unsigned int p) { return __uint_as_float(p & 0xffff0000u); }

// --- K0: fused prep: xcast | rowptr | wcast (block-range split) ------------
__global__ void prep_kernel(const float* __restrict__ x, uint4* __restrict__ xb4,
                            const int* __restrict__ rows, int* __restrict__ row_ptr,
                            const float* __restrict__ W, uint4* __restrict__ Wf,
                            int Nn, int Ee, int xcast_blks, int rowptr_blks) {
    int blk = blockIdx.x;
    if (blk < xcast_blks) {
        int i = blk * 256 + threadIdx.x;
        if (i < Nn * 16) {
            const f32x4_t* xf = (const f32x4_t*)x;           // read-once: NT
            f32x4_t f0 = __builtin_nontemporal_load(&xf[(size_t)i * 2]);
            f32x4_t f1 = __builtin_nontemporal_load(&xf[(size_t)i * 2 + 1]);
            u32x4_t o;
            o.x = pack2(f0.x, f0.y); o.y = pack2(f0.z, f0.w);
            o.z = pack2(f1.x, f1.y); o.w = pack2(f1.z, f1.w);
            __builtin_nontemporal_store(o, (u32x4_t*)&xb4[i]);
        }
    } else if (blk < xcast_blks + rowptr_blks) {
        int n = (blk - xcast_blks) * 256 + threadIdx.x;
        if (n <= Nn) {
            int lo = 0, hi = Ee;
            while (lo < hi) {
                int mid = (lo + hi) >> 1;
                if (rows[mid] < n) lo = mid + 1; else hi = mid;
            }
            row_ptr[n] = lo;
        }
    } else {
        int i = (blk - xcast_blks - rowptr_blks) * 256 + threadIdx.x;  // 0..4095
        int lane = i & 63, ks = (i >> 6) & 7, t = i >> 9;
        int row = t * 16 + (lane & 15);
        int col = ks * 32 + (lane >> 4) * 8;
        const float* p = W + (size_t)row * 256 + col;
        uint4 o;
        o.x = pack2(p[0], p[1]); o.y = pack2(p[2], p[3]);
        o.z = pack2(p[4], p[5]); o.w = pack2(p[6], p[7]);
        Wf[i] = o;                       // hot: every block re-reads -> cacheable
    }
}

// --- K1: fused agg + gemm + normalize --------------------------------------
// block = 256 thr = 4 waves, 16 nodes (grid 6250 exact).
// Phase 1 (agg): edges staged block-wide in LDS as {col|dest<<28, val}.
//   Wave w owns nodes 4w..4w+3 = contiguous edge range [rpS[4w],rpS[4w+4]).
//   Per edge: one 64-lane x 4B CONTIGUOUS gather of the source row (lane
//   holds features {2*lane, 2*lane+1}); f32x2 accumulate; flush to nbLDS
//   (pre-zeroed; covers deg-0) when dest changes. Ring of RING_D dword
//   loads, static unroll.
// Phase 2 (gemm): 16 rows, K=256 (self half from global xb, neighbor half
//   from LDS), 8 col-tiles split 2/wave; MFMA 16x16x32 bf16; cross-wave
//   norm reduction through 256B LDS; fused bias+normalize NT store.
__global__ void __launch_bounds__(256, 6)
fused_kernel(const int* __restrict__ row_ptr,
             const int* __restrict__ cols,
             const float* __restrict__ vals,
             const char* __restrict__ xbB,
             const bf16x8_t* __restrict__ Wf,
             const float* __restrict__ b,
             float* __restrict__ out, int Nn) {
    __shared__ int   rpS[17];
    __shared__ uint2 cvLDS[DESC_CAP];                     // 4 KB
    __shared__ uint4 nbLDS[16 * 17];                      // 4.25 KB
    __shared__ float __attribute__((aligned(16))) sqLDS[16][4];

    int lane = threadIdx.x & 63;
    int w    = threadIdx.x >> 6;
    int r0   = blockIdx.x * 16;

    if (threadIdx.x < 17)
        rpS[threadIdx.x] = row_ptr[min(r0 + (int)threadIdx.x, Nn)];
    __syncthreads();

    int eLo = rpS[0], eHi = rpS[16];
    int cnt = eHi - eLo;
    bool big = cnt > DESC_CAP;     // block-uniform; ~never on this input

    if (!big) {
        for (int i = threadIdx.x; i < cnt; i += 256) {
            int e = eLo + i;
            int c = __builtin_nontemporal_load(&cols[e]);
            float v = __builtin_nontemporal_load(&vals[e]);
            // dest = largest d in [0,15] with rpS[d] <= e  (branchless bisect)
            int d = (e >= rpS[8]) ? 8 : 0;
            d += (e >= rpS[d + 4]) ? 4 : 0;
            d += (e >= rpS[d + 2]) ? 2 : 0;
            d += (e >= rpS[d + 1]) ? 1 : 0;
            uint2 cv;
            cv.x = (unsigned)c | ((unsigned)d << 28);     // c < 2^17
            cv.y = __float_as_uint(v);
            cvLDS[i] = cv;
        }
    }
    {   // pre-zero nbLDS: deg-0 nodes (and fallback-skipped rows) stay zero
        unsigned* nz = (unsigned*)nbLDS;
        for (int i = threadIdx.x; i < 16 * 17 * 4; i += 256) nz[i] = 0u;
    }
    __syncthreads();

    // ---------------- phase 1: aggregate ----------------
    if (!big) {
        int wLo = __builtin_amdgcn_readfirstlane(rpS[w * 4]     - eLo);
        int wHi = __builtin_amdgcn_readfirstlane(rpS[w * 4 + 4] - eLo);
        int nEd = wHi - wLo;
        if (nEd > 0) {
            unsigned lane2 = (unsigned)lane << 2;
            int wHiM1 = wHi - 1;
            unsigned* nbW = (unsigned*)nbLDS;

            unsigned P[RING_D];
            uint2    cv[RING_D];
#pragma unroll
            for (int d = 0; d < RING_D; ++d) {            // prologue (clamped)
                int kd = min(wLo + d, wHiM1);
                cv[d] = cvLDS[kd];
                unsigned voff = ((cv[d].x & 0x0FFFFFFFu) << 8) | lane2;
                P[d] = *(const unsigned*)(xbB + voff);
            }
            int cur = (int)(cv[0].x >> 28);
            float ax = 0.f, ay = 0.f;

            int nit = (nEd + RING_D - 1) / RING_D;
            int k0 = wLo;
            for (int it = 0; it < nit; ++it, k0 += RING_D) {
#pragma unroll
                for (int d = 0; d < RING_D; ++d) {
                    int k = k0 + d;
                    uint2 cvk = cv[d];
                    int dk = (int)(cvk.x >> 28);
                    if (dk != cur) {                      // wave-uniform branch
                        nbW[cur * 68 + lane] = pack2(ax, ay);
                        ax = 0.f; ay = 0.f;
                        cur = dk;
                    }
                    float vv = (k < wHi) ? __uint_as_float(cvk.y) : 0.f;
                    unsigned Pd = P[d];                   // auto vmcnt(RING_D-1)
                    ax += vv * bflo(Pd);
                    ay += vv * bfhi(Pd);
                    uint2 cvn = cvLDS[min(k + RING_D, wHiM1)];
                    unsigned voff = ((cvn.x & 0x0FFFFFFFu) << 8) | lane2;
                    P[d] = *(const unsigned*)(xbB + voff);
                    cv[d] = cvn;
                }
            }
            nbW[cur * 68 + lane] = pack2(ax, ay);         // final flush
        }
    } else {
        // oversized block: proven register-pipelined fallback (Round 4 layout)
        int h = lane >> 4;            // node slot within wave
        int l = lane & 15;            // feature chunk [8l, 8l+8)
        int node = w * 4 + h;         // 0..15
        int n = r0 + node;
        int nn = min(n, Nn - 1);
        int start = row_ptr[nn], end = row_ptr[nn + 1];
        if (n >= Nn) end = start;
        unsigned loff = (unsigned)l << 4;

        f32x2_t a0 = {0.f, 0.f}, a1 = {0.f, 0.f}, a2 = {0.f, 0.f}, a3 = {0.f, 0.f};

#define ACC1(p, V) {                                                        \
        f32x2_t vv2 = {(V), (V)};                                           \
        f32x2_t t0 = {bflo((p).x), bfhi((p).x)};                            \
        f32x2_t t1 = {bflo((p).y), bfhi((p).y)};                            \
        f32x2_t t2 = {bflo((p).z), bfhi((p).z)};                            \
        f32x2_t t3 = {bflo((p).w), bfhi((p).w)};                            \
        a0 += vv2 * t0; a1 += vv2 * t1; a2 += vv2 * t2; a3 += vv2 * t3;     \
}
#define EDGE4B(E, C0, C1, C2, C3, V0, V1, V2, V3)                               \
        {                                                                       \
            int q0 = min((E), end - 1),     q1 = min((E) + 1, end - 1);         \
            int q2 = min((E) + 2, end - 1), q3 = min((E) + 3, end - 1);         \
            C0 = cols[q0]; C1 = cols[q1]; C2 = cols[q2]; C3 = cols[q3];         \
            V0 = ((E)     < end) ? vals[q0] : 0.f;                              \
            V1 = ((E) + 1 < end) ? vals[q1] : 0.f;                              \
            V2 = ((E) + 2 < end) ? vals[q2] : 0.f;                              \
            V3 = ((E) + 3 < end) ? vals[q3] : 0.f;                              \
        }
        int e = start;
        int c0 = 0, c1 = 0, c2 = 0, c3 = 0;
        float v0 = 0.f, v1 = 0.f, v2 = 0.f, v3 = 0.f;
        if (e < end) EDGE4B(e, c0, c1, c2, c3, v0, v1, v2, v3);
        while (e < end) {
            int en = e + 4;
            int d0 = 0, d1 = 0, d2 = 0, d3 = 0;
            float w0 = 0.f, w1 = 0.f, w2 = 0.f, w3 = 0.f;
            if (en < end) EDGE4B(en, d0, d1, d2, d3, w0, w1, w2, w3);
            uint4 p0 = *(const uint4*)(xbB + (((unsigned)c0 << 8) | loff));
            uint4 p1 = *(const uint4*)(xbB + (((unsigned)c1 << 8) | loff));
            uint4 p2 = *(const uint4*)(xbB + (((unsigned)c2 << 8) | loff));
            uint4 p3 = *(const uint4*)(xbB + (((unsigned)c3 << 8) | loff));
            ACC1(p0, v0); ACC1(p1, v1); ACC1(p2, v2); ACC1(p3, v3);
            c0 = d0; c1 = d1; c2 = d2; c3 = d3;
            v0 = w0; v1 = w1; v2 = w2; v3 = w3;
            e = en;
        }
#undef EDGE4B
#undef ACC1
        uint4 o;
        o.x = pack2(a0.x, a0.y); o.y = pack2(a1.x, a1.y);
        o.z = pack2(a2.x, a2.y); o.w = pack2(a3.x, a3.y);
        nbLDS[node * 17 + l] = o;
    }
    __syncthreads();

    // ---------------- phase 2: gemm + normalize ----------------
    int m    = lane & 15;
    int quad = lane >> 4;

    int arow = min(r0 + m, Nn - 1);
    const bf16x8_t* Ax = (const bf16x8_t*)(xbB + (size_t)arow * 256);

    bf16x8_t a[8];
#pragma unroll
    for (int ks = 0; ks < 4; ++ks) a[ks] = Ax[ks * 4 + quad];
#pragma unroll
    for (int ks = 0; ks < 4; ++ks)
        a[4 + ks] = *(const bf16x8_t*)&nbLDS[m * 17 + ks * 4 + quad];

    f32x4_t acc[2];
    float bc[2];
#pragma unroll
    for (int j = 0; j < 2; ++j) {
        int t = w * 2 + j;
        acc[j] = (f32x4_t){0.f, 0.f, 0.f, 0.f};
        bc[j]  = b[t * 16 + m];
#pragma unroll
        for (int ks = 0; ks < 8; ++ks) {
            acc[j] = __builtin_amdgcn_mfma_f32_16x16x32_bf16(
                a[ks], Wf[(t * 8 + ks) * 64 + lane], acc[j], 0, 0, 0);
        }
    }

    // per-row sum of squares: lane holds rows quad*4+r, cols (w*2+j)*16+m
    float sq[4] = {0.f, 0.f, 0.f, 0.f};
#pragma unroll
    for (int j = 0; j < 2; ++j)
#pragma unroll
        for (int r = 0; r < 4; ++r) {
            float u = acc[j][r] + bc[j];
            sq[r] += u * u;
        }
#pragma unroll
    for (int off = 1; off <= 8; off <<= 1) {
#pragma unroll
        for (int r = 0; r < 4; ++r) sq[r] += __shfl_xor(sq[r], off, 64);
    }
    if (m == 0) {
#pragma unroll
        for (int r = 0; r < 4; ++r) sqLDS[quad * 4 + r][w] = sq[r];
    }
    __syncthreads();

    float scale[4];
#pragma unroll
    for (int r = 0; r < 4; ++r) {
        const float4 q4 = *(const float4*)sqLDS[quad * 4 + r];
        float tot = q4.x + q4.y + q4.z + q4.w;
        scale[r] = 1.f / fmaxf(sqrtf(tot), 1e-12f);
    }

#pragma unroll
    for (int r = 0; r < 4; ++r) {
        int row = r0 + quad * 4 + r;
        if (row < Nn) {
            float* orow = out + (size_t)row * 128;
#pragma unroll
            for (int j = 0; j < 2; ++j) {
                int t = w * 2 + j;
                __builtin_nontemporal_store((acc[j][r] + bc[j]) * scale[r],
                                            &orow[t * 16 + m]);
            }
        }
    }
}

extern "C" void kernel_launch(void* const* d_in, const int* in_sizes, int n_in,
                              void* d_out, int out_size, void* d_ws, size_t ws_size,
                              hipStream_t stream) {
    const float* x    = (const float*)d_in[0];
    const int*   rows = (const int*)  d_in[1];
    const int*   cols = (const int*)  d_in[2];
    const float* vals = (const float*)d_in[3];
    const float* W    = (const float*)d_in[4];
    const float* b    = (const float*)d_in[5];
    float*       out  = (float*)d_out;

    const int Nn = in_sizes[0] / 128;    // 100000
    const int Ee = in_sizes[1];          // 1600000

    char*  ws      = (char*)d_ws;
    int*   row_ptr = (int*)ws;
    uint4* Wf      = (uint4*)(ws + 448 * 1024);
    uint4* xb      = (uint4*)(ws + 640 * 1024);

    const int xcast_blks  = (Nn * 16 + 255) / 256;   // 6250
    const int rowptr_blks = (Nn + 1 + 255) / 256;    // 391
    const int wcast_blks  = 16;

    prep_kernel<<<xcast_blks + rowptr_blks + wcast_blks, 256, 0, stream>>>(
        x, xb, rows, row_ptr, W, Wf, Nn, Ee, xcast_blks, rowptr_blks);
    fused_kernel<<<(Nn + 15) / 16, 256, 0, stream>>>(
        row_ptr, cols, vals, (const char*)xb,
        (const bf16x8_t*)Wf, b, out, Nn);
}